// Round 6
// baseline (1624.773 us; speedup 1.0000x reference)
//
#include <hip/hip_runtime.h>
#include <hip/hip_bf16.h>

#define NB 8
#define NP 8192
#define NC 6
#define NG 512
#define GS 32

#define CENTER_OFF (NB * NG * GS * NC)        /* 786432 */
#define IDX_OFF    (CENTER_OFF + NB * NG * 3) /* 798720 */

// RESOLVED DTYPE MODEL (fits all R0-R5 evidence):
//   d_in[0] : f32  (R5's inf proved bf16 reads were reinterpreting f32 words)
//   d_out   : f32  (R1/R2's 8194.39 = my bf16 idx writes landing, as pairs,
//                   inside the f32-indexed neighborhood chunk)
// All distance math: f32 _rn intrinsics in the reference's association order
// -> selections bit-match the np reference; outputs are exact.
// fps->knn handoff via d_ws ints; all gathered indices clamped to [0,NP) so
// no replay/poison state can cause an OOB access (R3/R4 abort lesson).

// ---------------------------------------------------------------------------
// Kernel 1: farthest-point sampling, one block (1024 thr) per batch.
// Writes f32 centers to d_out chunk 1 and center point indices to d_ws.
// ---------------------------------------------------------------------------
__global__ __launch_bounds__(1024) void fps_kernel(
    const float* __restrict__ xyz, float* __restrict__ out,
    int* __restrict__ cidx)
{
  __shared__ float sfx, sfy, sfz;
  __shared__ float redv[16];
  __shared__ int   redi[16];
  __shared__ int   sfar;

  const int b = blockIdx.x;
  const int tid = threadIdx.x;
  const float* base = xyz + (size_t)b * NP * NC;

  float px[8], py[8], pz[8], dv[8];
#pragma unroll
  for (int j = 0; j < 8; ++j) {
    const int p = tid + (j << 10);
    px[j] = base[p * 6 + 0];
    py[j] = base[p * 6 + 1];
    pz[j] = base[p * 6 + 2];
  }

  // first sample is index 0
  if (tid == 0) {
    sfx = px[0]; sfy = py[0]; sfz = pz[0];
    const size_t cb = (size_t)(b * NG + 0) * 3;
    out[CENTER_OFF + cb + 0] = px[0];
    out[CENTER_OFF + cb + 1] = py[0];
    out[CENTER_OFF + cb + 2] = pz[0];
    cidx[b * NG + 0] = 0;
  }
  __syncthreads();

  float cx = sfx, cy = sfy, cz = sfz;
  float lv = -__builtin_inff();
  int   li = 0x7fffffff;
#pragma unroll
  for (int j = 0; j < 8; ++j) {
    const float dx = __fsub_rn(px[j], cx);
    const float dy = __fsub_rn(py[j], cy);
    const float dz = __fsub_rn(pz[j], cz);
    const float d = __fadd_rn(
        __fadd_rn(__fmul_rn(dx, dx), __fmul_rn(dy, dy)), __fmul_rn(dz, dz));
    dv[j] = d;
    if (d > lv) { lv = d; li = tid + (j << 10); }  // strict >: first max
  }

  for (int it = 1; it < NG; ++it) {
    // block-wide lexicographic argmax (max value, tie -> min index)
    float v = lv; int i = li;
#pragma unroll
    for (int off = 32; off > 0; off >>= 1) {
      const float ov = __shfl_xor(v, off);
      const int   oi = __shfl_xor(i, off);
      if (ov > v || (ov == v && oi < i)) { v = ov; i = oi; }
    }
    const int wid = tid >> 6;
    if ((tid & 63) == 0) { redv[wid] = v; redi[wid] = i; }
    __syncthreads();
    if (tid == 0) {
      float gv = redv[0]; int gi = redi[0];
      for (int w = 1; w < 16; ++w) {
        if (redv[w] > gv || (redv[w] == gv && redi[w] < gi)) {
          gv = redv[w]; gi = redi[w];
        }
      }
      sfar = gi;
    }
    __syncthreads();
    const int far = sfar;
    if (tid == (far & 1023)) {
      const int jj = far >> 10;
      float fx = 0.f, fy = 0.f, fz = 0.f;
#pragma unroll
      for (int j = 0; j < 8; ++j)
        if (j == jj) { fx = px[j]; fy = py[j]; fz = pz[j]; }
      sfx = fx; sfy = fy; sfz = fz;
      const size_t cb = (size_t)(b * NG + it) * 3;
      out[CENTER_OFF + cb + 0] = fx;
      out[CENTER_OFF + cb + 1] = fy;
      out[CENTER_OFF + cb + 2] = fz;
      cidx[b * NG + it] = far;
    }
    __syncthreads();
    cx = sfx; cy = sfy; cz = sfz;

    lv = -__builtin_inff(); li = 0x7fffffff;
#pragma unroll
    for (int j = 0; j < 8; ++j) {
      const float dx = __fsub_rn(px[j], cx);
      const float dy = __fsub_rn(py[j], cy);
      const float dz = __fsub_rn(pz[j], cz);
      const float d = __fadd_rn(
          __fadd_rn(__fmul_rn(dx, dx), __fmul_rn(dy, dy)), __fmul_rn(dz, dz));
      dv[j] = fminf(dv[j], d);
      if (dv[j] > lv) { lv = dv[j]; li = tid + (j << 10); }
    }
  }
}

// ---------------------------------------------------------------------------
// Kernel 2: 32-NN per (batch, group) via 32 rounds of block argmin-with-
// removal (reproduces top_k ordering: ascending d2, ties -> lower index).
// One 256-thread block per (b,g); 32 d2 per thread in registers.
// d2 = (cc + xx) - 2*dot, sums left-to-right, _rn (no FMA contraction).
// ---------------------------------------------------------------------------
__global__ __launch_bounds__(256) void knn_kernel(
    const float* __restrict__ xyz, float* __restrict__ out,
    const int* __restrict__ cidx)
{
  __shared__ float redv[4];
  __shared__ int   redi[4];
  __shared__ int   swin;
  __shared__ int   winlist[GS];

  const int bg = blockIdx.x;
  const int b = bg >> 9;
  const int tid = threadIdx.x;
  const float* base = xyz + (size_t)b * NP * NC;

  const int pc = cidx[bg] & (NP - 1);  // clamp: fault-proof under any state
  const float cx = base[pc * 6 + 0];
  const float cy = base[pc * 6 + 1];
  const float cz = base[pc * 6 + 2];
  const float cc = __fadd_rn(
      __fadd_rn(__fmul_rn(cx, cx), __fmul_rn(cy, cy)), __fmul_rn(cz, cz));

  float dreg[32];
  float lv = __builtin_inff();
  int   li = 0x7fffffff;
#pragma unroll
  for (int j = 0; j < 32; ++j) {
    const int p = tid + (j << 8);
    const float x = base[p * 6 + 0];
    const float y = base[p * 6 + 1];
    const float z = base[p * 6 + 2];
    const float xx = __fadd_rn(
        __fadd_rn(__fmul_rn(x, x), __fmul_rn(y, y)), __fmul_rn(z, z));
    const float dot = __fadd_rn(
        __fadd_rn(__fmul_rn(cx, x), __fmul_rn(cy, y)), __fmul_rn(cz, z));
    const float d2 = __fsub_rn(__fadd_rn(cc, xx), __fmul_rn(2.0f, dot));
    dreg[j] = d2;
    if (d2 < lv) { lv = d2; li = p; }  // strict <: first min (lowest index)
  }

  for (int k = 0; k < GS; ++k) {
    float v = lv; int i = li;
#pragma unroll
    for (int off = 32; off > 0; off >>= 1) {
      const float ov = __shfl_xor(v, off);
      const int   oi = __shfl_xor(i, off);
      if (ov < v || (ov == v && oi < i)) { v = ov; i = oi; }
    }
    const int wid = tid >> 6;
    if ((tid & 63) == 0) { redv[wid] = v; redi[wid] = i; }
    __syncthreads();
    if (tid == 0) {
      float gv = redv[0]; int gi = redi[0];
      for (int w = 1; w < 4; ++w) {
        if (redv[w] < gv || (redv[w] == gv && redi[w] < gi)) {
          gv = redv[w]; gi = redi[w];
        }
      }
      winlist[k] = gi;
      swin = gi;
    }
    __syncthreads();
    const int gi = swin;
    if ((gi & 255) == tid) {
      const int wj = gi >> 8;
      lv = __builtin_inff(); li = 0x7fffffff;
#pragma unroll
      for (int j = 0; j < 32; ++j) {
        if (j == wj) dreg[j] = __builtin_inff();
        if (dreg[j] < lv) { lv = dreg[j]; li = tid + (j << 8); }
      }
    }
  }
  __syncthreads();

  if (tid < GS) {
    const int p = winlist[tid] & (NP - 1);  // in-bounds by construction
    const float v0 = base[p * 6 + 0];
    const float v1 = base[p * 6 + 1];
    const float v2 = base[p * 6 + 2];
    const size_t ob = ((size_t)bg * GS + tid) * 6;
    out[ob + 0] = __fsub_rn(v0, cx);
    out[ob + 1] = __fsub_rn(v1, cy);
    out[ob + 2] = __fsub_rn(v2, cz);
    out[ob + 3] = base[p * 6 + 3];  // extras: raw f32 passthrough
    out[ob + 4] = base[p * 6 + 4];
    out[ob + 5] = base[p * 6 + 5];
    out[IDX_OFF + (size_t)bg * GS + tid] = (float)p;  // idx as f32 value
  }
}

extern "C" void kernel_launch(void* const* d_in, const int* in_sizes, int n_in,
                              void* d_out, int out_size, void* d_ws,
                              size_t ws_size, hipStream_t stream)
{
  const float* xyz = (const float*)d_in[0];
  float* out = (float*)d_out;
  int* cidx = (int*)d_ws;  // NB*NG ints = 16 KiB scratch

  hipLaunchKernelGGL(fps_kernel, dim3(NB), dim3(1024), 0, stream,
                     xyz, out, cidx);
  hipLaunchKernelGGL(knn_kernel, dim3(NB * NG), dim3(256), 0, stream,
                     xyz, out, cidx);
}

// Round 7
// 1135.222 us; speedup vs baseline: 1.4312x; 1.4312x over previous
//
#include <hip/hip_runtime.h>
#include <hip/hip_bf16.h>

#define NB 8
#define NP 8192
#define NC 6
#define NG 512
#define GS 32

#define CENTER_OFF (NB * NG * GS * NC)        /* 786432 */
#define IDX_OFF    (CENTER_OFF + NB * NG * 3) /* 798720 */

// Dtypes (validated R6): d_in[0] f32, d_out f32. absmax 0.0 -> selection math
// bit-matches np reference. Keep: _rn intrinsics, left-to-right association,
// lexicographic tie-breaks (max dist -> min index; min d2 -> min index).

// ---------------------------------------------------------------------------
// Kernel 1: FPS, one block (512 thr = 8 waves) per batch. Latency-optimized:
//  - 1 barrier/iter (parity-buffered partials, all-thread redundant final
//    reduce of 8 wave partials)
//  - winner coords gathered from an LDS mirror of the points (96 KB)
//  - no global stores in the loop (sel[] in LDS, single epilogue write;
//    avoids the vmcnt(0) drain before every s_barrier)
// R6 counters: 6300 cyc/iter, VALU floor 768 -> predicted ~1500 cyc/iter.
// ---------------------------------------------------------------------------
__global__ __launch_bounds__(512) void fps_kernel(
    const float* __restrict__ xyz, float* __restrict__ out,
    int* __restrict__ cidx)
{
  __shared__ float lx[NP], ly[NP], lz[NP];   // 96 KB point mirror
  __shared__ float redv[2][8];
  __shared__ int   redi[2][8];
  __shared__ int   sel[NG];

  const int b = blockIdx.x;
  const int tid = threadIdx.x;
  const float* base = xyz + (size_t)b * NP * NC;

  float px[16], py[16], pz[16], dv[16];
#pragma unroll
  for (int j = 0; j < 16; ++j) {
    const int p = tid + (j << 9);
    px[j] = base[p * 6 + 0];
    py[j] = base[p * 6 + 1];
    pz[j] = base[p * 6 + 2];
    lx[p] = px[j]; ly[p] = py[j]; lz[p] = pz[j];
  }
  if (tid == 0) sel[0] = 0;
  __syncthreads();

  // center 0 = point 0
  float cx = lx[0], cy = ly[0], cz = lz[0];

  // initial distances + lane-local argmax (j ascending = index ascending,
  // strict > keeps first occurrence)
  float lv = -__builtin_inff();
  int   li = 0x7fffffff;
#pragma unroll
  for (int j = 0; j < 16; ++j) {
    const float dx = __fsub_rn(px[j], cx);
    const float dy = __fsub_rn(py[j], cy);
    const float dz = __fsub_rn(pz[j], cz);
    const float d = __fadd_rn(
        __fadd_rn(__fmul_rn(dx, dx), __fmul_rn(dy, dy)), __fmul_rn(dz, dz));
    dv[j] = d;
    if (d > lv) { lv = d; li = tid + (j << 9); }
  }

  for (int it = 1; it < NG; ++it) {
    // wave-level lexicographic argmax (max value, tie -> min index)
    float v = lv; int i = li;
#pragma unroll
    for (int off = 32; off > 0; off >>= 1) {
      const float ov = __shfl_xor(v, off);
      const int   oi = __shfl_xor(i, off);
      if (ov > v || (ov == v && oi < i)) { v = ov; i = oi; }
    }
    const int pb = it & 1;  // parity buffer: write@it vs read@it-2 separated
                            // by barrier@it-1 -> single barrier is safe
    if ((tid & 63) == 0) { redv[pb][tid >> 6] = v; redi[pb][tid >> 6] = i; }
    __syncthreads();

    // every thread reduces the 8 wave partials (identical result everywhere;
    // w ascending + strict > preserves min-index tie-break)
    float gv = redv[pb][0]; int gi = redi[pb][0];
#pragma unroll
    for (int w = 1; w < 8; ++w) {
      const float wv = redv[pb][w]; const int wi = redi[pb][w];
      if (wv > gv || (wv == gv && wi < gi)) { gv = wv; gi = wi; }
    }
    if (tid == 0) sel[it] = gi;

    // winner coords via LDS broadcast gather (no extra barrier)
    cx = lx[gi]; cy = ly[gi]; cz = lz[gi];

    // min-update + lane-local argmax for next iteration
    lv = -__builtin_inff(); li = 0x7fffffff;
#pragma unroll
    for (int j = 0; j < 16; ++j) {
      const float dx = __fsub_rn(px[j], cx);
      const float dy = __fsub_rn(py[j], cy);
      const float dz = __fsub_rn(pz[j], cz);
      const float d = __fadd_rn(
          __fadd_rn(__fmul_rn(dx, dx), __fmul_rn(dy, dy)), __fmul_rn(dz, dz));
      dv[j] = fminf(dv[j], d);
      if (dv[j] > lv) { lv = dv[j]; li = tid + (j << 9); }
    }
  }
  __syncthreads();

  // epilogue: 512 threads = NG groups; coalesced center + cidx writes
  {
    const int p = sel[tid];
    const size_t cb = (size_t)(b * NG + tid) * 3;
    out[CENTER_OFF + cb + 0] = lx[p];
    out[CENTER_OFF + cb + 1] = ly[p];
    out[CENTER_OFF + cb + 2] = lz[p];
    cidx[b * NG + tid] = p;
  }
}

// ---------------------------------------------------------------------------
// Kernel 2: 32-NN per (batch, group) — UNCHANGED from validated R6 version.
// ---------------------------------------------------------------------------
__global__ __launch_bounds__(256) void knn_kernel(
    const float* __restrict__ xyz, float* __restrict__ out,
    const int* __restrict__ cidx)
{
  __shared__ float redv[4];
  __shared__ int   redi[4];
  __shared__ int   swin;
  __shared__ int   winlist[GS];

  const int bg = blockIdx.x;
  const int b = bg >> 9;
  const int tid = threadIdx.x;
  const float* base = xyz + (size_t)b * NP * NC;

  const int pc = cidx[bg] & (NP - 1);  // clamp: fault-proof under any state
  const float cx = base[pc * 6 + 0];
  const float cy = base[pc * 6 + 1];
  const float cz = base[pc * 6 + 2];
  const float cc = __fadd_rn(
      __fadd_rn(__fmul_rn(cx, cx), __fmul_rn(cy, cy)), __fmul_rn(cz, cz));

  float dreg[32];
  float lv = __builtin_inff();
  int   li = 0x7fffffff;
#pragma unroll
  for (int j = 0; j < 32; ++j) {
    const int p = tid + (j << 8);
    const float x = base[p * 6 + 0];
    const float y = base[p * 6 + 1];
    const float z = base[p * 6 + 2];
    const float xx = __fadd_rn(
        __fadd_rn(__fmul_rn(x, x), __fmul_rn(y, y)), __fmul_rn(z, z));
    const float dot = __fadd_rn(
        __fadd_rn(__fmul_rn(cx, x), __fmul_rn(cy, y)), __fmul_rn(cz, z));
    const float d2 = __fsub_rn(__fadd_rn(cc, xx), __fmul_rn(2.0f, dot));
    dreg[j] = d2;
    if (d2 < lv) { lv = d2; li = p; }  // strict <: first min (lowest index)
  }

  for (int k = 0; k < GS; ++k) {
    float v = lv; int i = li;
#pragma unroll
    for (int off = 32; off > 0; off >>= 1) {
      const float ov = __shfl_xor(v, off);
      const int   oi = __shfl_xor(i, off);
      if (ov < v || (ov == v && oi < i)) { v = ov; i = oi; }
    }
    const int wid = tid >> 6;
    if ((tid & 63) == 0) { redv[wid] = v; redi[wid] = i; }
    __syncthreads();
    if (tid == 0) {
      float gv = redv[0]; int gi = redi[0];
      for (int w = 1; w < 4; ++w) {
        if (redv[w] < gv || (redv[w] == gv && redi[w] < gi)) {
          gv = redv[w]; gi = redi[w];
        }
      }
      winlist[k] = gi;
      swin = gi;
    }
    __syncthreads();
    const int gi = swin;
    if ((gi & 255) == tid) {
      const int wj = gi >> 8;
      lv = __builtin_inff(); li = 0x7fffffff;
#pragma unroll
      for (int j = 0; j < 32; ++j) {
        if (j == wj) dreg[j] = __builtin_inff();
        if (dreg[j] < lv) { lv = dreg[j]; li = tid + (j << 8); }
      }
    }
  }
  __syncthreads();

  if (tid < GS) {
    const int p = winlist[tid] & (NP - 1);  // in-bounds by construction
    const float v0 = base[p * 6 + 0];
    const float v1 = base[p * 6 + 1];
    const float v2 = base[p * 6 + 2];
    const size_t ob = ((size_t)bg * GS + tid) * 6;
    out[ob + 0] = __fsub_rn(v0, cx);
    out[ob + 1] = __fsub_rn(v1, cy);
    out[ob + 2] = __fsub_rn(v2, cz);
    out[ob + 3] = base[p * 6 + 3];  // extras: raw f32 passthrough
    out[ob + 4] = base[p * 6 + 4];
    out[ob + 5] = base[p * 6 + 5];
    out[IDX_OFF + (size_t)bg * GS + tid] = (float)p;  // idx as f32 value
  }
}

extern "C" void kernel_launch(void* const* d_in, const int* in_sizes, int n_in,
                              void* d_out, int out_size, void* d_ws,
                              size_t ws_size, hipStream_t stream)
{
  const float* xyz = (const float*)d_in[0];
  float* out = (float*)d_out;
  int* cidx = (int*)d_ws;  // NB*NG ints = 16 KiB scratch

  hipLaunchKernelGGL(fps_kernel, dim3(NB), dim3(512), 0, stream,
                     xyz, out, cidx);
  hipLaunchKernelGGL(knn_kernel, dim3(NB * NG), dim3(256), 0, stream,
                     xyz, out, cidx);
}

// Round 8
// 812.815 us; speedup vs baseline: 1.9989x; 1.3967x over previous
//
#include <hip/hip_runtime.h>
#include <hip/hip_bf16.h>

#define NB 8
#define NP 8192
#define NC 6
#define NG 512
#define GS 32

#define CENTER_OFF (NB * NG * GS * NC)        /* 786432 */
#define IDX_OFF    (CENTER_OFF + NB * NG * 3) /* 798720 */

// Dtypes (validated R6/R7): d_in[0] f32, d_out f32; absmax 0.0 with _rn math
// in the reference's association order. Selection logic everywhere is
// lexicographic and bit-exact vs the np reference.
//
// u64 keys: fps dist >= 0 -> IEEE bits are monotone; key = (bits<<32)|(8191-p)
// so u64 MAX = (max dist, tie -> min p). knn d2 can be NEGATIVE (expanded
// form cancellation), so bits get the standard sign-flip transform first;
// key = (flip(bits)<<32)|p so u64 MIN = (min d2, tie -> min p). -0.0 cannot
// occur (a-b with a==b gives +0.0 in RN), so flip's -0<+0 artifact is moot.

// ---------------------------------------------------------------------------
// Kernel 1: FPS. One block (1024 thr = 16 waves) per batch, 8 pts/thread.
// Per iteration: fmin-update (pipelined) -> 7-merge register tree ->
// 6-step wave shfl (u64) -> 1 ds_write_b64 -> ONE barrier (parity) ->
// 1 ds_read_b64 + 4-step xor-butterfly over 16 partials (all lanes converge)
// -> ds_read_b128 winner gather from float4 mirror. No global ops in loop.
// R7: 4000 cyc/iter (issue 1840 + stalls 2150). Target ~2200.
// ---------------------------------------------------------------------------
__global__ __launch_bounds__(1024) void fps_kernel(
    const float* __restrict__ xyz, float* __restrict__ out,
    int* __restrict__ cidx)
{
  __shared__ float4 mir[NP];                     // 128 KB point mirror
  __shared__ unsigned long long kpart[2][16];    // parity-buffered partials
  __shared__ int sel[NG];

  const int b = blockIdx.x;
  const int tid = threadIdx.x;
  const int lane = tid & 63;
  const int wave = tid >> 6;
  const float* base = xyz + (size_t)b * NP * NC;

  float px[8], py[8], pz[8], dv[8];
  unsigned int LO[8];  // 8191 - p (key low word), precomputed once
#pragma unroll
  for (int j = 0; j < 8; ++j) {
    const int p = tid + (j << 10);
    px[j] = base[p * 6 + 0];
    py[j] = base[p * 6 + 1];
    pz[j] = base[p * 6 + 2];
    mir[p] = make_float4(px[j], py[j], pz[j], 0.0f);
    LO[j] = (unsigned)(NP - 1 - p);
  }
  if (tid == 0) sel[0] = 0;
  __syncthreads();

  // center 0 = point 0 (broadcast read from mirror)
  float4 c0 = mir[0];
  float cx = c0.x, cy = c0.y, cz = c0.z;

  // initial distances (reference association: ((dx*dx+dy*dy)+dz*dz), _rn)
#pragma unroll
  for (int j = 0; j < 8; ++j) {
    const float dx = __fsub_rn(px[j], cx);
    const float dy = __fsub_rn(py[j], cy);
    const float dz = __fsub_rn(pz[j], cz);
    dv[j] = __fadd_rn(
        __fadd_rn(__fmul_rn(dx, dx), __fmul_rn(dy, dy)), __fmul_rn(dz, dz));
  }

  for (int it = 1; it < NG; ++it) {
    // build 8 keys, 7-merge tree (keys unique -> any merge order exact)
    unsigned long long k0, k1, k2, k3;
    {
      unsigned long long t[8];
#pragma unroll
      for (int j = 0; j < 8; ++j)
        t[j] = ((unsigned long long)__float_as_uint(dv[j]) << 32) | LO[j];
      k0 = t[0] > t[1] ? t[0] : t[1];
      k1 = t[2] > t[3] ? t[2] : t[3];
      k2 = t[4] > t[5] ? t[4] : t[5];
      k3 = t[6] > t[7] ? t[6] : t[7];
      k0 = k0 > k1 ? k0 : k1;
      k2 = k2 > k3 ? k2 : k3;
      k0 = k0 > k2 ? k0 : k2;
    }
    // wave-level u64 max (6-step xor butterfly)
#pragma unroll
    for (int off = 32; off; off >>= 1) {
      const unsigned long long ok = __shfl_xor(k0, off);
      if (ok > k0) k0 = ok;
    }
    const int pb = it & 1;
    if (lane == 0) kpart[pb][wave] = k0;
    __syncthreads();

    // cross-wave: each lane reads one of 16 partials, 4-step butterfly
    // within its 16-lane subgroup -> every lane holds the global max
    unsigned long long g = kpart[pb][lane & 15];
#pragma unroll
    for (int off = 1; off < 16; off <<= 1) {
      const unsigned long long og = __shfl_xor(g, off);
      if (og > g) g = og;
    }
    const int gi = (NP - 1) - (int)(unsigned)(g & 0xFFFFFFFFu);  // in [0,8191]
    if (tid == 0) sel[it] = gi;

    // winner coords: one ds_read_b128 broadcast
    const float4 c = mir[gi];
    cx = c.x; cy = c.y; cz = c.z;

    // min-update (pipelined; argmax deferred to next iter's key tree)
#pragma unroll
    for (int j = 0; j < 8; ++j) {
      const float dx = __fsub_rn(px[j], cx);
      const float dy = __fsub_rn(py[j], cy);
      const float dz = __fsub_rn(pz[j], cz);
      const float d = __fadd_rn(
          __fadd_rn(__fmul_rn(dx, dx), __fmul_rn(dy, dy)), __fmul_rn(dz, dz));
      dv[j] = fminf(dv[j], d);
    }
  }
  __syncthreads();

  // epilogue: threads 0..511 write centers + cidx
  if (tid < NG) {
    const int p = sel[tid];
    const float4 c = mir[p];
    const size_t cb = (size_t)(b * NG + tid) * 3;
    out[CENTER_OFF + cb + 0] = c.x;
    out[CENTER_OFF + cb + 1] = c.y;
    out[CENTER_OFF + cb + 2] = c.z;
    cidx[b * NG + tid] = p;
  }
}

// ---------------------------------------------------------------------------
// Kernel 2: 32-NN per (batch, group), 256 thr, 32 pts/thread in registers.
// Per round: u64 min-key wave shfl -> 1 ds_write -> ONE barrier (parity) ->
// all-thread 4-partial butterfly (no tid0 serialization, no broadcast
// barrier) -> owner rescan. Winner of round k kept in a register by thread k.
// Selection math unchanged from validated R6 (_rn, expanded-form d2).
// ---------------------------------------------------------------------------
__global__ __launch_bounds__(256) void knn_kernel(
    const float* __restrict__ xyz, float* __restrict__ out,
    const int* __restrict__ cidx)
{
  __shared__ unsigned long long kpart[2][4];

  const int bg = blockIdx.x;
  const int b = bg >> 9;
  const int tid = threadIdx.x;
  const int lane = tid & 63;
  const int wave = tid >> 6;
  const float* base = xyz + (size_t)b * NP * NC;

  const int pc = cidx[bg] & (NP - 1);  // clamp: fault-proof under any state
  const float cx = base[pc * 6 + 0];
  const float cy = base[pc * 6 + 1];
  const float cz = base[pc * 6 + 2];
  const float cc = __fadd_rn(
      __fadd_rn(__fmul_rn(cx, cx), __fmul_rn(cy, cy)), __fmul_rn(cz, cz));

  float dreg[32];
  float lv = __builtin_inff();
  int   li = 0x7fffffff;
#pragma unroll
  for (int j = 0; j < 32; ++j) {
    const int p = tid + (j << 8);
    const float x = base[p * 6 + 0];
    const float y = base[p * 6 + 1];
    const float z = base[p * 6 + 2];
    const float xx = __fadd_rn(
        __fadd_rn(__fmul_rn(x, x), __fmul_rn(y, y)), __fmul_rn(z, z));
    const float dot = __fadd_rn(
        __fadd_rn(__fmul_rn(cx, x), __fmul_rn(cy, y)), __fmul_rn(cz, z));
    const float d2 = __fsub_rn(__fadd_rn(cc, xx), __fmul_rn(2.0f, dot));
    dreg[j] = d2;
    if (d2 < lv) { lv = d2; li = p; }  // strict <: first min (lowest index)
  }

  int myp = 0;
  for (int k = 0; k < GS; ++k) {
    // build sortable min-key: sign-flip transform (d2 may be negative)
    unsigned int u = __float_as_uint(lv);
    u ^= ((unsigned)((int)u >> 31)) | 0x80000000u;
    unsigned long long key = ((unsigned long long)u << 32) | (unsigned)li;
#pragma unroll
    for (int off = 32; off; off >>= 1) {
      const unsigned long long ok = __shfl_xor(key, off);
      if (ok < key) key = ok;
    }
    const int pb = k & 1;
    if (lane == 0) kpart[pb][wave] = key;
    __syncthreads();

    unsigned long long g = kpart[pb][lane & 3];
#pragma unroll
    for (int off = 1; off < 4; off <<= 1) {
      const unsigned long long og = __shfl_xor(g, off);
      if (og < g) g = og;
    }
    const int p = (int)(unsigned)(g & 0xFFFFFFFFu);  // winner point index
    if (tid == k) myp = p;

    // owner invalidates + rescans its 32 (others' local min unchanged)
    if ((p & 255) == tid) {
      const int wj = p >> 8;
      lv = __builtin_inff(); li = 0x7fffffff;
#pragma unroll
      for (int j = 0; j < 32; ++j) {
        if (j == wj) dreg[j] = __builtin_inff();
        if (dreg[j] < lv) { lv = dreg[j]; li = tid + (j << 8); }
      }
    }
  }

  if (tid < GS) {
    const int p = myp & (NP - 1);  // in-bounds by construction
    const float v0 = base[p * 6 + 0];
    const float v1 = base[p * 6 + 1];
    const float v2 = base[p * 6 + 2];
    const size_t ob = ((size_t)bg * GS + tid) * 6;
    out[ob + 0] = __fsub_rn(v0, cx);
    out[ob + 1] = __fsub_rn(v1, cy);
    out[ob + 2] = __fsub_rn(v2, cz);
    out[ob + 3] = base[p * 6 + 3];  // extras: raw f32 passthrough
    out[ob + 4] = base[p * 6 + 4];
    out[ob + 5] = base[p * 6 + 5];
    out[IDX_OFF + (size_t)bg * GS + tid] = (float)p;  // idx as f32 value
  }
}

extern "C" void kernel_launch(void* const* d_in, const int* in_sizes, int n_in,
                              void* d_out, int out_size, void* d_ws,
                              size_t ws_size, hipStream_t stream)
{
  const float* xyz = (const float*)d_in[0];
  float* out = (float*)d_out;
  int* cidx = (int*)d_ws;  // NB*NG ints = 16 KiB scratch

  hipLaunchKernelGGL(fps_kernel, dim3(NB), dim3(1024), 0, stream,
                     xyz, out, cidx);
  hipLaunchKernelGGL(knn_kernel, dim3(NB * NG), dim3(256), 0, stream,
                     xyz, out, cidx);
}

// Round 9
// 808.277 us; speedup vs baseline: 2.0102x; 1.0056x over previous
//
#include <hip/hip_runtime.h>
#include <hip/hip_bf16.h>

#define NB 8
#define NP 8192
#define NC 6
#define NG 512
#define GS 32

#define CENTER_OFF (NB * NG * GS * NC)        /* 786432 */
#define IDX_OFF    (CENTER_OFF + NB * NG * 3) /* 798720 */

// Dtypes (validated R6-R8): d_in[0] f32, d_out f32; absmax 0.0 with _rn math
// in the reference's association order; u64 keys make every tie-break exact
// and total-ordered (fps: (dist_bits<<32)|(8191-p), max; knn: sign-flipped
// d2 bits <<32 | p, min; -0.0 impossible).

// ---------------------------------------------------------------------------
// Kernel 1: FPS. One block per batch. R9: 512 thr (8 waves, 16 pts/thread) —
// same u64/parity/single-barrier structure as R8@1024, isolating the
// thread-count variable (shorter barrier convergence, 8 partials, 3-step
// cross-butterfly). R8 measured 2865 cyc/iter (1790 issue + 1075 stall).
// ---------------------------------------------------------------------------
__global__ __launch_bounds__(512) void fps_kernel(
    const float* __restrict__ xyz, float* __restrict__ out,
    int* __restrict__ cidx)
{
  __shared__ float4 mir[NP];                    // 128 KB point mirror
  __shared__ unsigned long long kpart[2][8];    // parity-buffered partials
  __shared__ int sel[NG];

  const int b = blockIdx.x;
  const int tid = threadIdx.x;
  const int lane = tid & 63;
  const int wave = tid >> 6;
  const float* base = xyz + (size_t)b * NP * NC;

  float px[16], py[16], pz[16], dv[16];
  unsigned int LO[16];  // 8191 - p (key low word)
#pragma unroll
  for (int j = 0; j < 16; ++j) {
    const int p = tid + (j << 9);
    px[j] = base[p * 6 + 0];
    py[j] = base[p * 6 + 1];
    pz[j] = base[p * 6 + 2];
    mir[p] = make_float4(px[j], py[j], pz[j], 0.0f);
    LO[j] = (unsigned)(NP - 1 - p);
  }
  if (tid == 0) sel[0] = 0;
  __syncthreads();

  float4 c0 = mir[0];
  float cx = c0.x, cy = c0.y, cz = c0.z;

#pragma unroll
  for (int j = 0; j < 16; ++j) {
    const float dx = __fsub_rn(px[j], cx);
    const float dy = __fsub_rn(py[j], cy);
    const float dz = __fsub_rn(pz[j], cz);
    dv[j] = __fadd_rn(
        __fadd_rn(__fmul_rn(dx, dx), __fmul_rn(dy, dy)), __fmul_rn(dz, dz));
  }

  for (int it = 1; it < NG; ++it) {
    // 16 keys -> 15-merge tree (keys unique -> any merge order exact)
    unsigned long long k0;
    {
      unsigned long long t[16];
#pragma unroll
      for (int j = 0; j < 16; ++j)
        t[j] = ((unsigned long long)__float_as_uint(dv[j]) << 32) | LO[j];
#pragma unroll
      for (int s = 8; s; s >>= 1)
#pragma unroll
        for (int j = 0; j < s; ++j)
          t[j] = t[j] > t[j + s] ? t[j] : t[j + s];
      k0 = t[0];
    }
    // wave-level u64 max (6-step xor butterfly)
#pragma unroll
    for (int off = 32; off; off >>= 1) {
      const unsigned long long ok = __shfl_xor(k0, off);
      if (ok > k0) k0 = ok;
    }
    const int pb = it & 1;
    if (lane == 0) kpart[pb][wave] = k0;
    __syncthreads();

    // cross-wave: lane reads one of 8 partials, 3-step butterfly converges all
    unsigned long long g = kpart[pb][lane & 7];
#pragma unroll
    for (int off = 1; off < 8; off <<= 1) {
      const unsigned long long og = __shfl_xor(g, off);
      if (og > g) g = og;
    }
    const int gi = (NP - 1) - (int)(unsigned)(g & 0xFFFFFFFFu);
    if (tid == 0) sel[it] = gi;

    const float4 c = mir[gi];   // one ds_read_b128 broadcast
    cx = c.x; cy = c.y; cz = c.z;

#pragma unroll
    for (int j = 0; j < 16; ++j) {
      const float dx = __fsub_rn(px[j], cx);
      const float dy = __fsub_rn(py[j], cy);
      const float dz = __fsub_rn(pz[j], cz);
      const float d = __fadd_rn(
          __fadd_rn(__fmul_rn(dx, dx), __fmul_rn(dy, dy)), __fmul_rn(dz, dz));
      dv[j] = fminf(dv[j], d);
    }
  }
  __syncthreads();

  // epilogue: 512 threads = NG groups
  {
    const int p = sel[tid];
    const float4 c = mir[p];
    const size_t cb = (size_t)(b * NG + tid) * 3;
    out[CENTER_OFF + cb + 0] = c.x;
    out[CENTER_OFF + cb + 1] = c.y;
    out[CENTER_OFF + cb + 2] = c.z;
    cidx[b * NG + tid] = p;
  }
}

// ---------------------------------------------------------------------------
// Kernel 2: 32-NN per (batch, group). R9: BARRIER-FREE rounds.
// Each wave selects the exact top-32 of its own 2048 points via 32 shfl-only
// argmin rounds (owner-rescan incremental, as validated); wave 0 then merges
// the 4 sorted 32-lists (keys unique -> exact; output order = ascending key
// = lax.top_k order). 2 block barriers total (was 64).
// ---------------------------------------------------------------------------
__global__ __launch_bounds__(256) void knn_kernel(
    const float* __restrict__ xyz, float* __restrict__ out,
    const int* __restrict__ cidx)
{
  __shared__ unsigned long long kbuf[4 * GS];
  __shared__ int widx[GS];

  const int bg = blockIdx.x;
  const int b = bg >> 9;
  const int tid = threadIdx.x;
  const int lane = tid & 63;
  const int wave = tid >> 6;
  const float* base = xyz + (size_t)b * NP * NC;

  const int pc = cidx[bg] & (NP - 1);  // clamp: fault-proof under any state
  const float cx = base[pc * 6 + 0];
  const float cy = base[pc * 6 + 1];
  const float cz = base[pc * 6 + 2];
  const float cc = __fadd_rn(
      __fadd_rn(__fmul_rn(cx, cx), __fmul_rn(cy, cy)), __fmul_rn(cz, cz));

  float dreg[32];
  float lv = __builtin_inff();
  int   li = 0x7fffffff;
#pragma unroll
  for (int j = 0; j < 32; ++j) {
    const int p = tid + (j << 8);
    const float x = base[p * 6 + 0];
    const float y = base[p * 6 + 1];
    const float z = base[p * 6 + 2];
    const float xx = __fadd_rn(
        __fadd_rn(__fmul_rn(x, x), __fmul_rn(y, y)), __fmul_rn(z, z));
    const float dot = __fadd_rn(
        __fadd_rn(__fmul_rn(cx, x), __fmul_rn(cy, y)), __fmul_rn(cz, z));
    const float d2 = __fsub_rn(__fadd_rn(cc, xx), __fmul_rn(2.0f, dot));
    dreg[j] = d2;
    if (d2 < lv) { lv = d2; li = p; }  // strict <: first min (lowest index)
  }

  // 32 wave-local rounds, no barriers (this wave owns pts of tids
  // [64w, 64w+64), so each round's winner-owner is in this wave)
  unsigned long long wwin = 0;
  for (int k = 0; k < GS; ++k) {
    unsigned int u = __float_as_uint(lv);
    u ^= ((unsigned)((int)u >> 31)) | 0x80000000u;   // sign-flip: sortable min
    unsigned long long key = ((unsigned long long)u << 32) | (unsigned)li;
#pragma unroll
    for (int off = 32; off; off >>= 1) {
      const unsigned long long ok = __shfl_xor(key, off);
      if (ok < key) key = ok;
    }
    if (lane == k) wwin = key;                        // lane k: k-th smallest
    const int p = (int)(unsigned)(key & 0xFFFFFFFFu);
    if ((p & 255) == tid) {                           // owner rescans its 32
      const int wj = p >> 8;
      lv = __builtin_inff(); li = 0x7fffffff;
#pragma unroll
      for (int j = 0; j < 32; ++j) {
        if (j == wj) dreg[j] = __builtin_inff();
        if (dreg[j] < lv) { lv = dreg[j]; li = tid + (j << 8); }
      }
    }
  }
  if (lane < GS) kbuf[wave * GS + lane] = wwin;
  __syncthreads();

  // wave 0 merges the 4 sorted 32-lists: 32 argmin rounds over 128 keys
  if (wave == 0) {
    unsigned long long a = kbuf[lane];
    unsigned long long bb = kbuf[64 + lane];
    unsigned long long gwin = 0;
    for (int k = 0; k < GS; ++k) {
      unsigned long long g = a < bb ? a : bb;
#pragma unroll
      for (int off = 32; off; off >>= 1) {
        const unsigned long long og = __shfl_xor(g, off);
        if (og < g) g = og;
      }
      if (lane == k) gwin = g;
      if (a == g)  a  = ~0ull;   // keys unique: exactly one lane invalidates
      if (bb == g) bb = ~0ull;
    }
    if (lane < GS) widx[lane] = (int)(unsigned)(gwin & 0xFFFFFFFFu);
  }
  __syncthreads();

  if (tid < GS) {
    const int p = widx[tid] & (NP - 1);  // in-bounds by construction
    const float v0 = base[p * 6 + 0];
    const float v1 = base[p * 6 + 1];
    const float v2 = base[p * 6 + 2];
    const size_t ob = ((size_t)bg * GS + tid) * 6;
    out[ob + 0] = __fsub_rn(v0, cx);
    out[ob + 1] = __fsub_rn(v1, cy);
    out[ob + 2] = __fsub_rn(v2, cz);
    out[ob + 3] = base[p * 6 + 3];  // extras: raw f32 passthrough
    out[ob + 4] = base[p * 6 + 4];
    out[ob + 5] = base[p * 6 + 5];
    out[IDX_OFF + (size_t)bg * GS + tid] = (float)p;  // idx as f32 value
  }
}

extern "C" void kernel_launch(void* const* d_in, const int* in_sizes, int n_in,
                              void* d_out, int out_size, void* d_ws,
                              size_t ws_size, hipStream_t stream)
{
  const float* xyz = (const float*)d_in[0];
  float* out = (float*)d_out;
  int* cidx = (int*)d_ws;  // NB*NG ints = 16 KiB scratch

  hipLaunchKernelGGL(fps_kernel, dim3(NB), dim3(512), 0, stream,
                     xyz, out, cidx);
  hipLaunchKernelGGL(knn_kernel, dim3(NB * NG), dim3(256), 0, stream,
                     xyz, out, cidx);
}

// Round 10
// 808.141 us; speedup vs baseline: 2.0105x; 1.0002x over previous
//
#include <hip/hip_runtime.h>
#include <hip/hip_bf16.h>

#define NB 8
#define NP 8192
#define NC 6
#define NG 512
#define GS 32

#define CENTER_OFF (NB * NG * GS * NC)        /* 786432 */
#define IDX_OFF    (CENTER_OFF + NB * NG * 3) /* 798720 */

// Dtypes (validated R6-R9): d_in[0] f32, d_out f32; absmax 0.0 with _rn math
// in the reference's association order. Selection semantics everywhere:
// fps = (max dist, tie -> min idx); knn = (min d2, tie -> min idx), exact.
//
// R10: wave reductions via DPP (row_shr 1/2/4/8 + row_bcast 15/31) on the
// 32-bit sort value (u32 order == value order: fps dv>=0 raw bits; knn d2
// sign-flipped bits), winner arg resolved exactly by ballot+readlane with a
// rare-tie scalar loop. Cross-wave partials merged by register trees over
// broadcast LDS reads. No ds_bpermute anywhere (was ~500 cyc/chain).

#define DPP_MAX_U32(v, ctrl)                                               \
  {                                                                        \
    unsigned _m = (unsigned)__builtin_amdgcn_update_dpp(                   \
        (int)(v), (int)(v), (ctrl), 0xf, 0xf, false);                      \
    (v) = (_m > (v)) ? _m : (v);                                           \
  }
#define DPP_MIN_U32(v, ctrl)                                               \
  {                                                                        \
    unsigned _m = (unsigned)__builtin_amdgcn_update_dpp(                   \
        (int)(v), (int)(v), (ctrl), 0xf, 0xf, false);                      \
    (v) = (_m < (v)) ? _m : (v);                                           \
  }

// ---------------------------------------------------------------------------
// Kernel 1: FPS. One block (512 thr = 8 waves) per batch, 16 pts/thread.
// Per iter: u64 register tree (15 merges) -> 6-step DPP u32 max -> ballot
// arg-resolve -> lane0 ds_write -> ONE parity barrier -> 8-partial register
// tree (broadcast LDS reads) -> mir gather -> _rn min-update.
// R9: 2640 cyc/iter (issue ~1500, stall ~1140, ~500 = bpermute chain).
// ---------------------------------------------------------------------------
__global__ __launch_bounds__(512) void fps_kernel(
    const float* __restrict__ xyz, float* __restrict__ out,
    int* __restrict__ cidx)
{
  __shared__ float4 mir[NP];                    // 128 KB point mirror
  __shared__ unsigned long long kpart[2][8];    // parity-buffered partials
  __shared__ int sel[NG];

  const int b = blockIdx.x;
  const int tid = threadIdx.x;
  const int lane = tid & 63;
  const int wave = tid >> 6;
  const float* base = xyz + (size_t)b * NP * NC;

  float px[16], py[16], pz[16], dv[16];
  unsigned int LO[16];  // 8191 - p: u64-max tie-break = min point index
#pragma unroll
  for (int j = 0; j < 16; ++j) {
    const int p = tid + (j << 9);
    px[j] = base[p * 6 + 0];
    py[j] = base[p * 6 + 1];
    pz[j] = base[p * 6 + 2];
    mir[p] = make_float4(px[j], py[j], pz[j], 0.0f);
    LO[j] = (unsigned)(NP - 1 - p);
  }
  if (tid == 0) sel[0] = 0;
  __syncthreads();

  float4 c0 = mir[0];
  float cx = c0.x, cy = c0.y, cz = c0.z;

#pragma unroll
  for (int j = 0; j < 16; ++j) {
    const float dx = __fsub_rn(px[j], cx);
    const float dy = __fsub_rn(py[j], cy);
    const float dz = __fsub_rn(pz[j], cz);
    dv[j] = __fadd_rn(
        __fadd_rn(__fmul_rn(dx, dx), __fmul_rn(dy, dy)), __fmul_rn(dz, dz));
  }

  for (int it = 1; it < NG; ++it) {
    // per-thread u64 max tree (keys unique -> exact, any order)
    unsigned long long t[16];
#pragma unroll
    for (int j = 0; j < 16; ++j)
      t[j] = ((unsigned long long)__float_as_uint(dv[j]) << 32) | LO[j];
#pragma unroll
    for (int s = 8; s; s >>= 1)
#pragma unroll
      for (int j = 0; j < s; ++j)
        t[j] = t[j] > t[j + s] ? t[j] : t[j + s];
    const unsigned sv = (unsigned)(t[0] >> 32);  // dv>=0: bits order = value
    const unsigned lo = (unsigned)t[0];

    // wave max of sv via DPP (result in lane 63)
    unsigned r = sv;
    DPP_MAX_U32(r, 0x111); DPP_MAX_U32(r, 0x112); DPP_MAX_U32(r, 0x114);
    DPP_MAX_U32(r, 0x118); DPP_MAX_U32(r, 0x142); DPP_MAX_U32(r, 0x143);
    const unsigned smax = (unsigned)__builtin_amdgcn_readlane((int)r, 63);

    // arg resolve: tied lanes -> max LO (= min point idx); ties are rare
    const unsigned long long m = __ballot(sv == smax);
    unsigned wlo;
    if (m & (m - 1)) {
      unsigned long long mm = m; unsigned best = 0;
      while (mm) {
        const int l = __builtin_ctzll(mm);
        const unsigned c = (unsigned)__builtin_amdgcn_readlane((int)lo, l);
        if (c > best) best = c;
        mm &= mm - 1;
      }
      wlo = best;
    } else {
      wlo = (unsigned)__builtin_amdgcn_readlane((int)lo, __builtin_ctzll(m));
    }

    const int pb = it & 1;
    if (lane == 0)
      kpart[pb][wave] = ((unsigned long long)smax << 32) | wlo;
    __syncthreads();

    // cross-wave: broadcast LDS reads + register tree (no shfl)
    const unsigned long long* kp = kpart[pb];
    unsigned long long g0 = kp[0] > kp[1] ? kp[0] : kp[1];
    unsigned long long g1 = kp[2] > kp[3] ? kp[2] : kp[3];
    unsigned long long g2 = kp[4] > kp[5] ? kp[4] : kp[5];
    unsigned long long g3 = kp[6] > kp[7] ? kp[6] : kp[7];
    g0 = g0 > g1 ? g0 : g1;
    g2 = g2 > g3 ? g2 : g3;
    g0 = g0 > g2 ? g0 : g2;
    const int gi = (NP - 1) - (int)(unsigned)(g0 & 0xFFFFFFFFu);
    if (tid == 0) sel[it] = gi;

    const float4 c = mir[gi];   // one ds_read_b128 broadcast
    cx = c.x; cy = c.y; cz = c.z;

#pragma unroll
    for (int j = 0; j < 16; ++j) {
      const float dx = __fsub_rn(px[j], cx);
      const float dy = __fsub_rn(py[j], cy);
      const float dz = __fsub_rn(pz[j], cz);
      const float d = __fadd_rn(
          __fadd_rn(__fmul_rn(dx, dx), __fmul_rn(dy, dy)), __fmul_rn(dz, dz));
      dv[j] = fminf(dv[j], d);
    }
  }
  __syncthreads();

  // epilogue: 512 threads = NG groups
  {
    const int p = sel[tid];
    const float4 c = mir[p];
    const size_t cb = (size_t)(b * NG + tid) * 3;
    out[CENTER_OFF + cb + 0] = c.x;
    out[CENTER_OFF + cb + 1] = c.y;
    out[CENTER_OFF + cb + 2] = c.z;
    cidx[b * NG + tid] = p;
  }
}

// ---------------------------------------------------------------------------
// Kernel 2: 32-NN per (batch, group). R8 topology (block-wide rounds, single
// owner rescan) + R10 machinery: DPP u32 min (sign-flipped d2 bits) + ballot
// arg-resolve; cross-wave 4-partial register tree; owner rescan = dead-mask
// + 5-level argmin tree (left-wins-ties == serial first-min). One parity
// barrier per round.
// ---------------------------------------------------------------------------
__global__ __launch_bounds__(256) void knn_kernel(
    const float* __restrict__ xyz, float* __restrict__ out,
    const int* __restrict__ cidx)
{
  __shared__ unsigned long long kpart[2][4];

  const int bg = blockIdx.x;
  const int b = bg >> 9;
  const int tid = threadIdx.x;
  const int lane = tid & 63;
  const int wave = tid >> 6;
  const float* base = xyz + (size_t)b * NP * NC;

  const int pc = cidx[bg] & (NP - 1);  // clamp: fault-proof under any state
  const float cx = base[pc * 6 + 0];
  const float cy = base[pc * 6 + 1];
  const float cz = base[pc * 6 + 2];
  const float cc = __fadd_rn(
      __fadd_rn(__fmul_rn(cx, cx), __fmul_rn(cy, cy)), __fmul_rn(cz, cz));

  float dreg[32];
  float lv = __builtin_inff();
  int   li = 0x7fffffff;
#pragma unroll
  for (int j = 0; j < 32; ++j) {
    const int p = tid + (j << 8);
    const float x = base[p * 6 + 0];
    const float y = base[p * 6 + 1];
    const float z = base[p * 6 + 2];
    const float xx = __fadd_rn(
        __fadd_rn(__fmul_rn(x, x), __fmul_rn(y, y)), __fmul_rn(z, z));
    const float dot = __fadd_rn(
        __fadd_rn(__fmul_rn(cx, x), __fmul_rn(cy, y)), __fmul_rn(cz, z));
    const float d2 = __fsub_rn(__fadd_rn(cc, xx), __fmul_rn(2.0f, dot));
    dreg[j] = d2;
    if (d2 < lv) { lv = d2; li = p; }  // strict <: first min (lowest index)
  }

  unsigned dead = 0;
  int myp = 0;
  for (int k = 0; k < GS; ++k) {
    // sortable u32: sign-flip (d2 may be negative; -0 impossible)
    unsigned fv = __float_as_uint(lv);
    fv ^= ((unsigned)((int)fv >> 31)) | 0x80000000u;

    unsigned r = fv;
    DPP_MIN_U32(r, 0x111); DPP_MIN_U32(r, 0x112); DPP_MIN_U32(r, 0x114);
    DPP_MIN_U32(r, 0x118); DPP_MIN_U32(r, 0x142); DPP_MIN_U32(r, 0x143);
    const unsigned smin = (unsigned)__builtin_amdgcn_readlane((int)r, 63);

    const unsigned long long m = __ballot(fv == smin);
    unsigned wli;
    if (m & (m - 1)) {
      unsigned long long mm = m; unsigned best = 0xFFFFFFFFu;
      while (mm) {
        const int l = __builtin_ctzll(mm);
        const unsigned c = (unsigned)__builtin_amdgcn_readlane(li, l);
        if (c < best) best = c;
        mm &= mm - 1;
      }
      wli = best;
    } else {
      wli = (unsigned)__builtin_amdgcn_readlane(li, __builtin_ctzll(m));
    }

    const int pb = k & 1;
    if (lane == 0)
      kpart[pb][wave] = ((unsigned long long)smin << 32) | wli;
    __syncthreads();

    const unsigned long long* kp = kpart[pb];
    unsigned long long g0 = kp[0] < kp[1] ? kp[0] : kp[1];
    unsigned long long g1 = kp[2] < kp[3] ? kp[2] : kp[3];
    g0 = g0 < g1 ? g0 : g1;
    const int p = (int)(unsigned)(g0 & 0xFFFFFFFFu);  // winner point index
    if (tid == k) myp = p;

    // owner: kill winner slot, rebuild (lv, li) via argmin tree
    if ((p & 255) == tid) {
      dead |= 1u << (p >> 8);
      float v0[32];
#pragma unroll
      for (int j = 0; j < 32; ++j)
        v0[j] = ((dead >> j) & 1u) ? __builtin_inff() : dreg[j];
      float v1[16]; int j1[16];
#pragma unroll
      for (int s = 0; s < 16; ++s) {
        const bool tt = v0[2 * s + 1] < v0[2 * s];  // strict: left wins ties
        v1[s] = tt ? v0[2 * s + 1] : v0[2 * s];
        j1[s] = tt ? 2 * s + 1 : 2 * s;
      }
      float v2[8]; int j2[8];
#pragma unroll
      for (int s = 0; s < 8; ++s) {
        const bool tt = v1[2 * s + 1] < v1[2 * s];
        v2[s] = tt ? v1[2 * s + 1] : v1[2 * s];
        j2[s] = tt ? j1[2 * s + 1] : j1[2 * s];
      }
      float v3[4]; int j3[4];
#pragma unroll
      for (int s = 0; s < 4; ++s) {
        const bool tt = v2[2 * s + 1] < v2[2 * s];
        v3[s] = tt ? v2[2 * s + 1] : v2[2 * s];
        j3[s] = tt ? j2[2 * s + 1] : j2[2 * s];
      }
      float v4[2]; int j4[2];
#pragma unroll
      for (int s = 0; s < 2; ++s) {
        const bool tt = v3[2 * s + 1] < v3[2 * s];
        v4[s] = tt ? v3[2 * s + 1] : v3[2 * s];
        j4[s] = tt ? j3[2 * s + 1] : j3[2 * s];
      }
      const bool tt = v4[1] < v4[0];
      lv = tt ? v4[1] : v4[0];
      li = tid + ((tt ? j4[1] : j4[0]) << 8);
    }
  }

  if (tid < GS) {
    const int p = myp & (NP - 1);  // in-bounds by construction
    const float v0 = base[p * 6 + 0];
    const float v1 = base[p * 6 + 1];
    const float v2 = base[p * 6 + 2];
    const size_t ob = ((size_t)bg * GS + tid) * 6;
    out[ob + 0] = __fsub_rn(v0, cx);
    out[ob + 1] = __fsub_rn(v1, cy);
    out[ob + 2] = __fsub_rn(v2, cz);
    out[ob + 3] = base[p * 6 + 3];  // extras: raw f32 passthrough
    out[ob + 4] = base[p * 6 + 4];
    out[ob + 5] = base[p * 6 + 5];
    out[IDX_OFF + (size_t)bg * GS + tid] = (float)p;  // idx as f32 value
  }
}

extern "C" void kernel_launch(void* const* d_in, const int* in_sizes, int n_in,
                              void* d_out, int out_size, void* d_ws,
                              size_t ws_size, hipStream_t stream)
{
  const float* xyz = (const float*)d_in[0];
  float* out = (float*)d_out;
  int* cidx = (int*)d_ws;  // NB*NG ints = 16 KiB scratch

  hipLaunchKernelGGL(fps_kernel, dim3(NB), dim3(512), 0, stream,
                     xyz, out, cidx);
  hipLaunchKernelGGL(knn_kernel, dim3(NB * NG), dim3(256), 0, stream,
                     xyz, out, cidx);
}

// Round 11
// 663.944 us; speedup vs baseline: 2.4472x; 1.2172x over previous
//
#include <hip/hip_runtime.h>
#include <hip/hip_bf16.h>

#define NB 8
#define NP 8192
#define NC 6
#define NG 512
#define GS 32

#define CENTER_OFF (NB * NG * GS * NC)        /* 786432 */
#define IDX_OFF    (CENTER_OFF + NB * NG * 3) /* 798720 */

// Dtypes (validated R6-R10): d_in[0] f32, d_out f32; absmax 0.0 with _rn math
// in the reference's association order. Selection semantics: fps = (max dist,
// tie -> min idx); knn = (min d2, tie -> min idx) == lax.top_k stable order,
// realized as unique u64 keys (fps: (bits<<32)|(8191-p) max; knn:
// (signflip(bits)<<32)|p min; -0.0 impossible).

#define DPP_MAX_U32(v, ctrl)                                               \
  {                                                                        \
    unsigned _m = (unsigned)__builtin_amdgcn_update_dpp(                   \
        (int)(v), (int)(v), (ctrl), 0xf, 0xf, false);                      \
    (v) = (_m > (v)) ? _m : (v);                                           \
  }
#define DPP_MIN_U32(v, ctrl)                                               \
  {                                                                        \
    unsigned _m = (unsigned)__builtin_amdgcn_update_dpp(                   \
        (int)(v), (int)(v), (ctrl), 0xf, 0xf, false);                      \
    (v) = (_m < (v)) ? _m : (v);                                           \
  }

// ---------------------------------------------------------------------------
// Kernel 1: FPS — UNCHANGED from R10 (550 us; isolated this round).
// ---------------------------------------------------------------------------
__global__ __launch_bounds__(512) void fps_kernel(
    const float* __restrict__ xyz, float* __restrict__ out,
    int* __restrict__ cidx)
{
  __shared__ float4 mir[NP];
  __shared__ unsigned long long kpart[2][8];
  __shared__ int sel[NG];

  const int b = blockIdx.x;
  const int tid = threadIdx.x;
  const int lane = tid & 63;
  const int wave = tid >> 6;
  const float* base = xyz + (size_t)b * NP * NC;

  float px[16], py[16], pz[16], dv[16];
  unsigned int LO[16];
#pragma unroll
  for (int j = 0; j < 16; ++j) {
    const int p = tid + (j << 9);
    px[j] = base[p * 6 + 0];
    py[j] = base[p * 6 + 1];
    pz[j] = base[p * 6 + 2];
    mir[p] = make_float4(px[j], py[j], pz[j], 0.0f);
    LO[j] = (unsigned)(NP - 1 - p);
  }
  if (tid == 0) sel[0] = 0;
  __syncthreads();

  float4 c0 = mir[0];
  float cx = c0.x, cy = c0.y, cz = c0.z;

#pragma unroll
  for (int j = 0; j < 16; ++j) {
    const float dx = __fsub_rn(px[j], cx);
    const float dy = __fsub_rn(py[j], cy);
    const float dz = __fsub_rn(pz[j], cz);
    dv[j] = __fadd_rn(
        __fadd_rn(__fmul_rn(dx, dx), __fmul_rn(dy, dy)), __fmul_rn(dz, dz));
  }

  for (int it = 1; it < NG; ++it) {
    unsigned long long t[16];
#pragma unroll
    for (int j = 0; j < 16; ++j)
      t[j] = ((unsigned long long)__float_as_uint(dv[j]) << 32) | LO[j];
#pragma unroll
    for (int s = 8; s; s >>= 1)
#pragma unroll
      for (int j = 0; j < s; ++j)
        t[j] = t[j] > t[j + s] ? t[j] : t[j + s];
    const unsigned sv = (unsigned)(t[0] >> 32);
    const unsigned lo = (unsigned)t[0];

    unsigned r = sv;
    DPP_MAX_U32(r, 0x111); DPP_MAX_U32(r, 0x112); DPP_MAX_U32(r, 0x114);
    DPP_MAX_U32(r, 0x118); DPP_MAX_U32(r, 0x142); DPP_MAX_U32(r, 0x143);
    const unsigned smax = (unsigned)__builtin_amdgcn_readlane((int)r, 63);

    const unsigned long long m = __ballot(sv == smax);
    unsigned wlo;
    if (m & (m - 1)) {
      unsigned long long mm = m; unsigned best = 0;
      while (mm) {
        const int l = __builtin_ctzll(mm);
        const unsigned c = (unsigned)__builtin_amdgcn_readlane((int)lo, l);
        if (c > best) best = c;
        mm &= mm - 1;
      }
      wlo = best;
    } else {
      wlo = (unsigned)__builtin_amdgcn_readlane((int)lo, __builtin_ctzll(m));
    }

    const int pb = it & 1;
    if (lane == 0)
      kpart[pb][wave] = ((unsigned long long)smax << 32) | wlo;
    __syncthreads();

    const unsigned long long* kp = kpart[pb];
    unsigned long long g0 = kp[0] > kp[1] ? kp[0] : kp[1];
    unsigned long long g1 = kp[2] > kp[3] ? kp[2] : kp[3];
    unsigned long long g2 = kp[4] > kp[5] ? kp[4] : kp[5];
    unsigned long long g3 = kp[6] > kp[7] ? kp[6] : kp[7];
    g0 = g0 > g1 ? g0 : g1;
    g2 = g2 > g3 ? g2 : g3;
    g0 = g0 > g2 ? g0 : g2;
    const int gi = (NP - 1) - (int)(unsigned)(g0 & 0xFFFFFFFFu);
    if (tid == 0) sel[it] = gi;

    const float4 c = mir[gi];
    cx = c.x; cy = c.y; cz = c.z;

#pragma unroll
    for (int j = 0; j < 16; ++j) {
      const float dx = __fsub_rn(px[j], cx);
      const float dy = __fsub_rn(py[j], cy);
      const float dz = __fsub_rn(pz[j], cz);
      const float d = __fadd_rn(
          __fadd_rn(__fmul_rn(dx, dx), __fmul_rn(dy, dy)), __fmul_rn(dz, dz));
      dv[j] = fminf(dv[j], d);
    }
  }
  __syncthreads();

  {
    const int p = sel[tid];
    const float4 c = mir[p];
    const size_t cb = (size_t)(b * NG + tid) * 3;
    out[CENTER_OFF + cb + 0] = c.x;
    out[CENTER_OFF + cb + 1] = c.y;
    out[CENTER_OFF + cb + 2] = c.z;
    cidx[b * NG + tid] = p;
  }
}

// ---------------------------------------------------------------------------
// Kernel 2: 32-NN, R11 redesign: histogram-select + tiny-pool extraction.
// (1) 2048-bin histogram of fv>>21 (monotone in fv = sign-flipped d2 bits)
// (2) find bin B holding the 32nd-smallest key (shfl_up scan + refines)
// (3) compact: bin<B -> winners (<=31 by construction), bin==B -> candidates
// (4) wave 0 extracts 32 smallest u64 keys from the <=256 register pool via
//     DPP-min + ballot (R10-validated), zero barriers in the rounds.
// Exact: u64 keys unique & totally ordered; filter is rank-exact.
// ---------------------------------------------------------------------------
__global__ __launch_bounds__(256) void knn_kernel(
    const float* __restrict__ xyz, float* __restrict__ out,
    const int* __restrict__ cidx)
{
  __shared__ unsigned bins[2048];
  __shared__ unsigned part[256];
  __shared__ int sB;
  __shared__ unsigned wcnt, ccnt;
  __shared__ unsigned long long wbuf[32];
  __shared__ unsigned long long cbuf[224];
  __shared__ int widx[GS];

  const int bg = blockIdx.x;
  const int b = bg >> 9;
  const int tid = threadIdx.x;
  const int lane = tid & 63;
  const int wave = tid >> 6;
  const float* base = xyz + (size_t)b * NP * NC;

  const int pc = cidx[bg] & (NP - 1);  // clamp: fault-proof under any state
  const float cx = base[pc * 6 + 0];
  const float cy = base[pc * 6 + 1];
  const float cz = base[pc * 6 + 2];
  const float cc = __fadd_rn(
      __fadd_rn(__fmul_rn(cx, cx), __fmul_rn(cy, cy)), __fmul_rn(cz, cz));

  for (int i = tid; i < 2048; i += 256) bins[i] = 0;
  if (tid == 0) { wcnt = 0; ccnt = 0; }
  __syncthreads();

  unsigned fv[32];
#pragma unroll
  for (int j = 0; j < 32; ++j) {
    const int p = tid + (j << 8);
    const float x = base[p * 6 + 0];
    const float y = base[p * 6 + 1];
    const float z = base[p * 6 + 2];
    const float xx = __fadd_rn(
        __fadd_rn(__fmul_rn(x, x), __fmul_rn(y, y)), __fmul_rn(z, z));
    const float dot = __fadd_rn(
        __fadd_rn(__fmul_rn(cx, x), __fmul_rn(cy, y)), __fmul_rn(cz, z));
    const float d2 = __fsub_rn(__fadd_rn(cc, xx), __fmul_rn(2.0f, dot));
    unsigned u = __float_as_uint(d2);
    u ^= ((unsigned)((int)u >> 31)) | 0x80000000u;  // sortable (d2 can be <0)
    fv[j] = u;
    atomicAdd(&bins[u >> 21], 1u);
  }
  __syncthreads();

  unsigned s = 0;
#pragma unroll
  for (int i = 0; i < 8; ++i) s += bins[tid * 8 + i];
  part[tid] = s;
  __syncthreads();

  // wave 0: locate the bin containing the 32nd-smallest key
  if (wave == 0) {
    const unsigned q = part[4 * lane + 0] + part[4 * lane + 1] +
                       part[4 * lane + 2] + part[4 * lane + 3];
    unsigned cum = q;
#pragma unroll
    for (int off = 1; off < 64; off <<= 1) {
      const unsigned t = __shfl_up(cum, (unsigned)off);
      if (lane >= off) cum += t;
    }
    const unsigned long long mb = __ballot(cum >= 32u);
    const int ls = __builtin_ctzll(mb);           // crossing 32-bin chunk
    unsigned run = (unsigned)__builtin_amdgcn_readlane((int)cum, ls) -
                   (unsigned)__builtin_amdgcn_readlane((int)q, ls);
    const int t0 = 4 * ls;
    const unsigned p0 = part[t0 + 0], p1 = part[t0 + 1];
    const unsigned p2 = part[t0 + 2], p3 = part[t0 + 3];
    int ti = t0;
    if (run + p0 < 32u) {
      run += p0; ti = t0 + 1;
      if (run + p1 < 32u) {
        run += p1; ti = t0 + 2;
        if (run + p2 < 32u) { run += p2; ti = t0 + 3; (void)p3; }
      }
    }
    const int bb = ti * 8;
    unsigned h[8];
#pragma unroll
    for (int i = 0; i < 8; ++i) h[i] = bins[bb + i];
    int B = bb;
    for (int i = 0; i < 8; ++i) {          // uniform; crossing guaranteed
      if (run + h[i] >= 32u) { B = bb + i; break; }
      run += h[i];
    }
    if (lane == 0) sB = B;
  }
  __syncthreads();
  const int B = sB;

  // compact winners (bin<B) and candidates (bin==B)
#pragma unroll
  for (int j = 0; j < 32; ++j) {
    const int bin = (int)(fv[j] >> 21);
    if (bin <= B) {
      const unsigned long long key =
          ((unsigned long long)fv[j] << 32) | (unsigned)(tid + (j << 8));
      if (bin < B) {
        const unsigned pos = atomicAdd(&wcnt, 1u);
        if (pos < 32u) wbuf[pos] = key;
      } else {
        const unsigned pos = atomicAdd(&ccnt, 1u);
        if (pos < 224u) cbuf[pos] = key;
      }
    }
  }
  __syncthreads();

  // wave 0: extract 32 smallest u64 keys from the pool (no barriers)
  if (wave == 0) {
    const int W = (int)wcnt;     // <= 31 by construction of B
    const int C = (int)ccnt;
    unsigned long long pool[4];
#pragma unroll
    for (int rr = 0; rr < 4; ++rr) {
      const int i = lane + (rr << 6);
      unsigned long long k = ~0ull;
      if (i < W) k = wbuf[i];
      else if (i - W < C && i - W < 224) k = cbuf[i - W];
      pool[rr] = k;
    }
    unsigned long long l0 = pool[0] < pool[1] ? pool[0] : pool[1];
    unsigned long long l1 = pool[2] < pool[3] ? pool[2] : pool[3];
    unsigned long long loc = l0 < l1 ? l0 : l1;

    unsigned long long mykey = 0;
    for (int k = 0; k < GS; ++k) {
      const unsigned hi = (unsigned)(loc >> 32);
      unsigned r = hi;
      DPP_MIN_U32(r, 0x111); DPP_MIN_U32(r, 0x112); DPP_MIN_U32(r, 0x114);
      DPP_MIN_U32(r, 0x118); DPP_MIN_U32(r, 0x142); DPP_MIN_U32(r, 0x143);
      const unsigned minhi = (unsigned)__builtin_amdgcn_readlane((int)r, 63);

      const unsigned long long m = __ballot(hi == minhi);
      unsigned lo;
      if (m & (m - 1)) {                       // value tie: min low word
        unsigned long long mm = m; unsigned best = 0xFFFFFFFFu;
        while (mm) {
          const int l = __builtin_ctzll(mm);
          const unsigned c =
              (unsigned)__builtin_amdgcn_readlane((int)(unsigned)loc, l);
          if (c < best) best = c;
          mm &= mm - 1;
        }
        lo = best;
      } else {
        lo = (unsigned)__builtin_amdgcn_readlane((int)(unsigned)loc,
                                                 __builtin_ctzll(m));
      }
      const unsigned long long win = ((unsigned long long)minhi << 32) | lo;
      if (lane == k) mykey = win;
      if (loc == win) {                        // unique owner (keys unique)
#pragma unroll
        for (int rr = 0; rr < 4; ++rr)
          if (pool[rr] == win) pool[rr] = ~0ull;
        l0 = pool[0] < pool[1] ? pool[0] : pool[1];
        l1 = pool[2] < pool[3] ? pool[2] : pool[3];
        loc = l0 < l1 ? l0 : l1;
      }
    }
    if (lane < GS) widx[lane] = (int)(unsigned)(mykey & 0xFFFFFFFFu);
  }
  __syncthreads();

  if (tid < GS) {
    const int p = widx[tid] & (NP - 1);  // in-bounds by construction
    const float v0 = base[p * 6 + 0];
    const float v1 = base[p * 6 + 1];
    const float v2 = base[p * 6 + 2];
    const size_t ob = ((size_t)bg * GS + tid) * 6;
    out[ob + 0] = __fsub_rn(v0, cx);
    out[ob + 1] = __fsub_rn(v1, cy);
    out[ob + 2] = __fsub_rn(v2, cz);
    out[ob + 3] = base[p * 6 + 3];  // extras: raw f32 passthrough
    out[ob + 4] = base[p * 6 + 4];
    out[ob + 5] = base[p * 6 + 5];
    out[IDX_OFF + (size_t)bg * GS + tid] = (float)p;  // idx as f32 value
  }
}

extern "C" void kernel_launch(void* const* d_in, const int* in_sizes, int n_in,
                              void* d_out, int out_size, void* d_ws,
                              size_t ws_size, hipStream_t stream)
{
  const float* xyz = (const float*)d_in[0];
  float* out = (float*)d_out;
  int* cidx = (int*)d_ws;  // NB*NG ints = 16 KiB scratch

  hipLaunchKernelGGL(fps_kernel, dim3(NB), dim3(512), 0, stream,
                     xyz, out, cidx);
  hipLaunchKernelGGL(knn_kernel, dim3(NB * NG), dim3(256), 0, stream,
                     xyz, out, cidx);
}

// Round 12
// 620.330 us; speedup vs baseline: 2.6192x; 1.0703x over previous
//
#include <hip/hip_runtime.h>
#include <hip/hip_bf16.h>

#define NB 8
#define NP 8192
#define NC 6
#define NG 512
#define GS 32

#define CENTER_OFF (NB * NG * GS * NC)        /* 786432 */
#define IDX_OFF    (CENTER_OFF + NB * NG * 3) /* 798720 */

// Dtypes (validated R6-R11): d_in[0] f32, d_out f32; _rn math in the
// reference's association order. Selection: fps = (max dist, tie -> min idx);
// knn = (min d2, tie -> min idx) == lax.top_k stable order. u64 keys unique.
// R11 post-mortem: absmax 48 attributed to cbuf 224-cap overflow (edge
// centers -> dense bin B). R12: two-level histogram refinement makes the
// candidate bin 2048x narrower; winners run1+run2 <= 31 guaranteed.

#define DPP_MAX_U32(v, ctrl)                                               \
  {                                                                        \
    unsigned _m = (unsigned)__builtin_amdgcn_update_dpp(                   \
        (int)(v), (int)(v), (ctrl), 0xf, 0xf, false);                      \
    (v) = (_m > (v)) ? _m : (v);                                           \
  }
#define DPP_MIN_U32(v, ctrl)                                               \
  {                                                                        \
    unsigned _m = (unsigned)__builtin_amdgcn_update_dpp(                   \
        (int)(v), (int)(v), (ctrl), 0xf, 0xf, false);                      \
    (v) = (_m < (v)) ? _m : (v);                                           \
  }

// ---------------------------------------------------------------------------
// Kernel 1: FPS. R12: 256 thr (4 waves, 1/SIMD), 32 pts/thread; f32 max-tree
// + first-j scan replaces the u64 key tree (shorter issue + dep chain);
// DPP max + ballot arg-resolve (R10-validated); kpart[2][4] parity buffers,
// ONE barrier/iter; float4 LDS mirror for winner gather; epilogue writes.
// ---------------------------------------------------------------------------
__global__ __launch_bounds__(256) void fps_kernel(
    const float* __restrict__ xyz, float* __restrict__ out,
    int* __restrict__ cidx)
{
  __shared__ float4 mir[NP];                    // 128 KB point mirror
  __shared__ unsigned long long kpart[2][4];
  __shared__ int sel[NG];

  const int b = blockIdx.x;
  const int tid = threadIdx.x;
  const int lane = tid & 63;
  const int wave = tid >> 6;
  const float* base = xyz + (size_t)b * NP * NC;

  float px[32], py[32], pz[32], dv[32];
#pragma unroll
  for (int j = 0; j < 32; ++j) {
    const int p = tid + (j << 8);
    px[j] = base[p * 6 + 0];
    py[j] = base[p * 6 + 1];
    pz[j] = base[p * 6 + 2];
    mir[p] = make_float4(px[j], py[j], pz[j], 0.0f);
  }
  if (tid == 0) sel[0] = 0;
  __syncthreads();

  float4 c0 = mir[0];
  float cx = c0.x, cy = c0.y, cz = c0.z;

#pragma unroll
  for (int j = 0; j < 32; ++j) {
    const float dx = __fsub_rn(px[j], cx);
    const float dy = __fsub_rn(py[j], cy);
    const float dz = __fsub_rn(pz[j], cz);
    dv[j] = __fadd_rn(
        __fadd_rn(__fmul_rn(dx, dx), __fmul_rn(dy, dy)), __fmul_rn(dz, dz));
  }

  for (int it = 1; it < NG; ++it) {
    // f32 max tree (fmax returns an input bit-exactly; dv >= 0, no NaN)
    float t[16];
#pragma unroll
    for (int j = 0; j < 16; ++j) t[j] = fmaxf(dv[j], dv[j + 16]);
#pragma unroll
    for (int s = 8; s; s >>= 1)
#pragma unroll
      for (int j = 0; j < s; ++j) t[j] = fmaxf(t[j], t[j + s]);
    const float m = t[0];
    // first j with dv[j]==m (descending loop -> smallest j wins = min p)
    int jj = 0;
#pragma unroll
    for (int j = 31; j >= 0; --j)
      if (dv[j] == m) jj = j;
    const unsigned lo = (unsigned)(NP - 1 - tid - (jj << 8));  // 8191 - p

    // wave max of m's bits (dv>=0: u32 order == f32 order)
    const unsigned sv = __float_as_uint(m);
    unsigned r = sv;
    DPP_MAX_U32(r, 0x111); DPP_MAX_U32(r, 0x112); DPP_MAX_U32(r, 0x114);
    DPP_MAX_U32(r, 0x118); DPP_MAX_U32(r, 0x142); DPP_MAX_U32(r, 0x143);
    const unsigned smax = (unsigned)__builtin_amdgcn_readlane((int)r, 63);

    const unsigned long long mk = __ballot(sv == smax);
    unsigned wlo;
    if (mk & (mk - 1)) {          // value tie across lanes: max lo = min p
      unsigned long long mm = mk; unsigned best = 0;
      while (mm) {
        const int l = __builtin_ctzll(mm);
        const unsigned c = (unsigned)__builtin_amdgcn_readlane((int)lo, l);
        if (c > best) best = c;
        mm &= mm - 1;
      }
      wlo = best;
    } else {
      wlo = (unsigned)__builtin_amdgcn_readlane((int)lo, __builtin_ctzll(mk));
    }

    const int pb = it & 1;
    if (lane == 0)
      kpart[pb][wave] = ((unsigned long long)smax << 32) | wlo;
    __syncthreads();

    const unsigned long long* kp = kpart[pb];
    unsigned long long g0 = kp[0] > kp[1] ? kp[0] : kp[1];
    unsigned long long g1 = kp[2] > kp[3] ? kp[2] : kp[3];
    g0 = g0 > g1 ? g0 : g1;
    const int gi = (NP - 1) - (int)(unsigned)(g0 & 0xFFFFFFFFu);
    if (tid == 0) sel[it] = gi;

    const float4 c = mir[gi];     // one ds_read_b128 broadcast
    cx = c.x; cy = c.y; cz = c.z;

#pragma unroll
    for (int j = 0; j < 32; ++j) {
      const float dx = __fsub_rn(px[j], cx);
      const float dy = __fsub_rn(py[j], cy);
      const float dz = __fsub_rn(pz[j], cz);
      const float d = __fadd_rn(
          __fadd_rn(__fmul_rn(dx, dx), __fmul_rn(dy, dy)), __fmul_rn(dz, dz));
      dv[j] = fminf(dv[j], d);
    }
  }
  __syncthreads();

  for (int g = tid; g < NG; g += 256) {
    const int p = sel[g];
    const float4 c = mir[p];
    const size_t cb = (size_t)(b * NG + g) * 3;
    out[CENTER_OFF + cb + 0] = c.x;
    out[CENTER_OFF + cb + 1] = c.y;
    out[CENTER_OFF + cb + 2] = c.z;
    cidx[b * NG + g] = p;
  }
}

// ---------------------------------------------------------------------------
// Kernel 2: 32-NN, R12: TWO-LEVEL histogram select + tiny-pool extraction.
// L1: 2048 bins of fv>>21 -> bin B1 + run1 (count below).
// L2: re-histogram bin-B1 keys on (fv>>10)&0x7FF -> B2 + run2.
// Winners (< B1, or ==B1 with mid<B2): run1+run2 <= 31. Candidates
// ((fv>>10)==(B1<<11|B2)): ~1-8 expected (2^-13-octave slice), cap 224.
// Wave 0 extracts the 32 smallest u64 keys (DPP+ballot, R10-validated).
// ---------------------------------------------------------------------------
__global__ __launch_bounds__(256) void knn_kernel(
    const float* __restrict__ xyz, float* __restrict__ out,
    const int* __restrict__ cidx)
{
  __shared__ unsigned bins[2048];
  __shared__ unsigned part[256];
  __shared__ int sB, sRun;
  __shared__ unsigned wcnt, ccnt;
  __shared__ unsigned long long wbuf[32];
  __shared__ unsigned long long cbuf[224];
  __shared__ int widx[GS];

  const int bg = blockIdx.x;
  const int b = bg >> 9;
  const int tid = threadIdx.x;
  const int lane = tid & 63;
  const int wave = tid >> 6;
  const float* base = xyz + (size_t)b * NP * NC;

  const int pc = cidx[bg] & (NP - 1);  // clamp: fault-proof under any state
  const float cx = base[pc * 6 + 0];
  const float cy = base[pc * 6 + 1];
  const float cz = base[pc * 6 + 2];
  const float cc = __fadd_rn(
      __fadd_rn(__fmul_rn(cx, cx), __fmul_rn(cy, cy)), __fmul_rn(cz, cz));

  for (int i = tid; i < 2048; i += 256) bins[i] = 0;
  if (tid == 0) { wcnt = 0; ccnt = 0; }
  __syncthreads();

  unsigned fv[32];
#pragma unroll
  for (int j = 0; j < 32; ++j) {
    const int p = tid + (j << 8);
    const float x = base[p * 6 + 0];
    const float y = base[p * 6 + 1];
    const float z = base[p * 6 + 2];
    const float xx = __fadd_rn(
        __fadd_rn(__fmul_rn(x, x), __fmul_rn(y, y)), __fmul_rn(z, z));
    const float dot = __fadd_rn(
        __fadd_rn(__fmul_rn(cx, x), __fmul_rn(cy, y)), __fmul_rn(cz, z));
    const float d2 = __fsub_rn(__fadd_rn(cc, xx), __fmul_rn(2.0f, dot));
    unsigned u = __float_as_uint(d2);
    u ^= ((unsigned)((int)u >> 31)) | 0x80000000u;  // sortable (d2 can be <0)
    fv[j] = u;
    atomicAdd(&bins[u >> 21], 1u);
  }
  __syncthreads();

  // ---- Level 1: bin containing rank 32 ----
  {
    unsigned s = 0;
#pragma unroll
    for (int i = 0; i < 8; ++i) s += bins[tid * 8 + i];
    part[tid] = s;
  }
  __syncthreads();
  if (wave == 0) {
    const unsigned q = part[4 * lane + 0] + part[4 * lane + 1] +
                       part[4 * lane + 2] + part[4 * lane + 3];
    unsigned cum = q;
#pragma unroll
    for (int off = 1; off < 64; off <<= 1) {
      const unsigned t = __shfl_up(cum, (unsigned)off);
      if (lane >= off) cum += t;
    }
    const unsigned long long mb = __ballot(cum >= 32u);
    const int ls = __builtin_ctzll(mb);
    unsigned run = (unsigned)__builtin_amdgcn_readlane((int)cum, ls) -
                   (unsigned)__builtin_amdgcn_readlane((int)q, ls);
    unsigned h[32];
#pragma unroll
    for (int i = 0; i < 32; ++i) h[i] = bins[(ls << 5) + i];  // broadcast
    int T = ls << 5;
#pragma unroll
    for (int i = 0; i < 32; ++i) {
      if (run + h[i] >= 32u) { T = (ls << 5) + i; break; }
      run += h[i];
    }
    if (lane == 0) { sB = T; sRun = (int)run; }
  }
  __syncthreads();
  const int B1 = sB;
  const unsigned run1 = (unsigned)sRun;
  const unsigned r2 = 32u - run1;              // rank within bin B1, in [1,32]
  __syncthreads();

  // ---- Level 2: refine within bin B1 on bits 20..10 ----
  for (int i = tid; i < 2048; i += 256) bins[i] = 0;
  __syncthreads();
#pragma unroll
  for (int j = 0; j < 32; ++j)
    if ((int)(fv[j] >> 21) == B1) atomicAdd(&bins[(fv[j] >> 10) & 0x7FF], 1u);
  __syncthreads();
  {
    unsigned s = 0;
#pragma unroll
    for (int i = 0; i < 8; ++i) s += bins[tid * 8 + i];
    part[tid] = s;
  }
  __syncthreads();
  if (wave == 0) {
    const unsigned q = part[4 * lane + 0] + part[4 * lane + 1] +
                       part[4 * lane + 2] + part[4 * lane + 3];
    unsigned cum = q;
#pragma unroll
    for (int off = 1; off < 64; off <<= 1) {
      const unsigned t = __shfl_up(cum, (unsigned)off);
      if (lane >= off) cum += t;
    }
    const unsigned long long mb = __ballot(cum >= r2);  // total >= r2 always
    const int ls = __builtin_ctzll(mb);
    unsigned run = (unsigned)__builtin_amdgcn_readlane((int)cum, ls) -
                   (unsigned)__builtin_amdgcn_readlane((int)q, ls);
    unsigned h[32];
#pragma unroll
    for (int i = 0; i < 32; ++i) h[i] = bins[(ls << 5) + i];
    int T = ls << 5;
#pragma unroll
    for (int i = 0; i < 32; ++i) {
      if (run + h[i] >= r2) { T = (ls << 5) + i; break; }
      run += h[i];
    }
    if (lane == 0) { sB = T; sRun = (int)run; }
  }
  __syncthreads();
  const int B2 = sB;                            // run1 + sRun <= 31 winners
  const unsigned key22 = ((unsigned)B1 << 11) | (unsigned)B2;

  // ---- compaction ----
#pragma unroll
  for (int j = 0; j < 32; ++j) {
    const unsigned hi11 = fv[j] >> 21;
    const unsigned top22 = fv[j] >> 10;
    if (top22 <= key22) {
      const unsigned long long key =
          ((unsigned long long)fv[j] << 32) | (unsigned)(tid + (j << 8));
      if (top22 < key22) {
        if ((int)hi11 < B1 || hi11 == (unsigned)B1) {  // always true; winners
          const unsigned pos = atomicAdd(&wcnt, 1u);
          if (pos < 32u) wbuf[pos] = key;
        }
      } else {
        const unsigned pos = atomicAdd(&ccnt, 1u);
        if (pos < 224u) cbuf[pos] = key;
      }
    }
  }
  __syncthreads();

  // ---- wave 0: extract 32 smallest u64 keys from the pool ----
  if (wave == 0) {
    const int W = (int)(wcnt < 32u ? wcnt : 32u);     // provably <= 31
    const int C = (int)(ccnt < 224u ? ccnt : 224u);
    unsigned long long pool[4];
#pragma unroll
    for (int rr = 0; rr < 4; ++rr) {
      const int i = lane + (rr << 6);
      unsigned long long k = ~0ull;
      if (i < W) k = wbuf[i];
      else if (i - W < C) k = cbuf[i - W];
      pool[rr] = k;
    }
    unsigned long long l0 = pool[0] < pool[1] ? pool[0] : pool[1];
    unsigned long long l1 = pool[2] < pool[3] ? pool[2] : pool[3];
    unsigned long long loc = l0 < l1 ? l0 : l1;

    unsigned long long mykey = 0;
    for (int k = 0; k < GS; ++k) {
      const unsigned hi = (unsigned)(loc >> 32);
      unsigned r = hi;
      DPP_MIN_U32(r, 0x111); DPP_MIN_U32(r, 0x112); DPP_MIN_U32(r, 0x114);
      DPP_MIN_U32(r, 0x118); DPP_MIN_U32(r, 0x142); DPP_MIN_U32(r, 0x143);
      const unsigned minhi = (unsigned)__builtin_amdgcn_readlane((int)r, 63);

      const unsigned long long m = __ballot(hi == minhi);
      unsigned lo;
      if (m & (m - 1)) {                       // value tie: min low word
        unsigned long long mm = m; unsigned best = 0xFFFFFFFFu;
        while (mm) {
          const int l = __builtin_ctzll(mm);
          const unsigned c =
              (unsigned)__builtin_amdgcn_readlane((int)(unsigned)loc, l);
          if (c < best) best = c;
          mm &= mm - 1;
        }
        lo = best;
      } else {
        lo = (unsigned)__builtin_amdgcn_readlane((int)(unsigned)loc,
                                                 __builtin_ctzll(m));
      }
      const unsigned long long win = ((unsigned long long)minhi << 32) | lo;
      if (lane == k) mykey = win;
      if (loc == win) {                        // unique owner (keys unique)
#pragma unroll
        for (int rr = 0; rr < 4; ++rr)
          if (pool[rr] == win) pool[rr] = ~0ull;
        l0 = pool[0] < pool[1] ? pool[0] : pool[1];
        l1 = pool[2] < pool[3] ? pool[2] : pool[3];
        loc = l0 < l1 ? l0 : l1;
      }
    }
    if (lane < GS) widx[lane] = (int)(unsigned)(mykey & 0xFFFFFFFFu);
  }
  __syncthreads();

  if (tid < GS) {
    const int p = widx[tid] & (NP - 1);  // in-bounds by construction
    const float v0 = base[p * 6 + 0];
    const float v1 = base[p * 6 + 1];
    const float v2 = base[p * 6 + 2];
    const size_t ob = ((size_t)bg * GS + tid) * 6;
    out[ob + 0] = __fsub_rn(v0, cx);
    out[ob + 1] = __fsub_rn(v1, cy);
    out[ob + 2] = __fsub_rn(v2, cz);
    out[ob + 3] = base[p * 6 + 3];  // extras: raw f32 passthrough
    out[ob + 4] = base[p * 6 + 4];
    out[ob + 5] = base[p * 6 + 5];
    out[IDX_OFF + (size_t)bg * GS + tid] = (float)p;  // idx as f32 value
  }
}

extern "C" void kernel_launch(void* const* d_in, const int* in_sizes, int n_in,
                              void* d_out, int out_size, void* d_ws,
                              size_t ws_size, hipStream_t stream)
{
  const float* xyz = (const float*)d_in[0];
  float* out = (float*)d_out;
  int* cidx = (int*)d_ws;  // NB*NG ints = 16 KiB scratch

  hipLaunchKernelGGL(fps_kernel, dim3(NB), dim3(256), 0, stream,
                     xyz, out, cidx);
  hipLaunchKernelGGL(knn_kernel, dim3(NB * NG), dim3(256), 0, stream,
                     xyz, out, cidx);
}